// Round 5
// baseline (890.740 us; speedup 1.0000x reference)
//
#include <hip/hip_runtime.h>
#include <hip/hip_cooperative_groups.h>

namespace cg = cooperative_groups;

// Problem constants (reference shape (64,1,480,640) fp32)
#define B_SAMPLES 64
#define F4PS      76800                 // float4 per sample
#define BPB       32                    // blocks per sample
#define NBLK      (B_SAMPLES * BPB)     // 2048 blocks = 8/CU on 256 CUs
#define F4PB      (F4PS / BPB)          // 2400 float4 per block
#define TPB       256
#define FULL_IT   (F4PB / TPB)          // 9 full iterations
#define TAILN     (F4PB - FULL_IT*TPB)  // 96 tail float4 (threads < 96)
#define EPS_DET   1e-6f

__device__ __forceinline__ bool finitef(float x) {
    return (__float_as_uint(x) & 0x7f800000u) != 0x7f800000u;
}

// One fused cooperative kernel:
//  phase 0: mask-layout detect (blocks 0..15 scan first 256 KiB)
//  phase 1: per-block masked sums {n, sum_p, sum_t, sum_p2, sum_pt}
//  phase 2: per-block solve (a,b) from own sample's partials; residual pass
//  phase 3: block 0 final reduction -> out
__global__ void __launch_bounds__(TPB, 8)
fused(const float* __restrict__ pred, const float* __restrict__ target,
      const unsigned char* __restrict__ mask, int* __restrict__ flag,
      float* __restrict__ partials, float* __restrict__ rpart,
      float* __restrict__ out) {
    cg::grid_group grid = cg::this_grid();
    __shared__ float smem[4096];        // 16 KB multi-purpose

    const int s    = blockIdx.x >> 5;   // sample
    const int sub  = blockIdx.x & 31;   // sub-block within sample
    const int base4 = s * F4PS + sub * F4PB;
    const float4* p4 = (const float4*)pred;
    const float4* t4 = (const float4*)target;
    const int lane = threadIdx.x & 63;
    const int w    = threadIdx.x >> 6;

    // ---------------- phase 0: layout detect ----------------
    // int32 0/1 => bytes at 4k+{1,2,3} all zero; byte-bool => ~half nonzero.
    if (blockIdx.x < 16) {
        const uint4* m16 = (const uint4*)mask;
        unsigned v = 0;
        const int b = blockIdx.x * TPB + threadIdx.x;    // 4096 threads
#pragma unroll
        for (int k = 0; k < 4; ++k) {
            uint4 m = m16[b + k * 4096];                 // 256 KiB total
            v |= (m.x | m.y | m.z | m.w) & 0xffffff00u;
        }
        if (v) atomicOr(flag, 1);
    }
    grid.sync();

    const bool byteLayout = (*flag != 0);

    // ---------------- phase 1: masked sums ----------------
    float n = 0.f, sp = 0.f, st = 0.f, sp2 = 0.f, spt = 0.f;
    auto accum = [&](float p, float t, bool mv) {
        bool ok = mv && finitef(p) && finitef(t);
        float pv = ok ? p : 0.f;
        float tv = ok ? t : 0.f;
        n   += ok ? 1.f : 0.f;
        sp  += pv;
        st  += tv;
        sp2 += pv * pv;
        spt += pv * tv;
    };

    if (byteLayout) {
        const unsigned* m4 = (const unsigned*)mask;
        for (int k = 0; k < FULL_IT; ++k) {
            const int i4 = base4 + k * TPB + threadIdx.x;
            float4 p = p4[i4]; float4 t = t4[i4]; unsigned mm = m4[i4];
            accum(p.x, t.x, (mm & 0x000000ffu) != 0);
            accum(p.y, t.y, (mm & 0x0000ff00u) != 0);
            accum(p.z, t.z, (mm & 0x00ff0000u) != 0);
            accum(p.w, t.w, (mm & 0xff000000u) != 0);
        }
        if (threadIdx.x < TAILN) {
            const int i4 = base4 + FULL_IT * TPB + threadIdx.x;
            float4 p = p4[i4]; float4 t = t4[i4]; unsigned mm = m4[i4];
            accum(p.x, t.x, (mm & 0x000000ffu) != 0);
            accum(p.y, t.y, (mm & 0x0000ff00u) != 0);
            accum(p.z, t.z, (mm & 0x00ff0000u) != 0);
            accum(p.w, t.w, (mm & 0xff000000u) != 0);
        }
    } else {
        const int4* m4 = (const int4*)mask;
        for (int k = 0; k < FULL_IT; ++k) {
            const int i4 = base4 + k * TPB + threadIdx.x;
            float4 p = p4[i4]; float4 t = t4[i4]; int4 mm = m4[i4];
            accum(p.x, t.x, mm.x != 0);
            accum(p.y, t.y, mm.y != 0);
            accum(p.z, t.z, mm.z != 0);
            accum(p.w, t.w, mm.w != 0);
        }
        if (threadIdx.x < TAILN) {
            const int i4 = base4 + FULL_IT * TPB + threadIdx.x;
            float4 p = p4[i4]; float4 t = t4[i4]; int4 mm = m4[i4];
            accum(p.x, t.x, mm.x != 0);
            accum(p.y, t.y, mm.y != 0);
            accum(p.z, t.z, mm.z != 0);
            accum(p.w, t.w, mm.w != 0);
        }
    }

    // block reduce 5 quantities -> partials[blockIdx.x*5 + q]
    {
        float vals[5] = {n, sp, st, sp2, spt};
#pragma unroll
        for (int q = 0; q < 5; ++q) {
            float v = vals[q];
#pragma unroll
            for (int off = 32; off; off >>= 1) v += __shfl_xor(v, off);
            if (lane == 0) smem[w * 5 + q] = v;
        }
        __syncthreads();
        if (threadIdx.x == 0) {
#pragma unroll
            for (int q = 0; q < 5; ++q)
                partials[(size_t)blockIdx.x * 5 + q] =
                    smem[q] + smem[5 + q] + smem[10 + q] + smem[15 + q];
        }
    }
    __threadfence();   // make partials visible device-wide (cross-XCD)
    grid.sync();

    // ---------------- phase 2: solve + residual ----------------
    // wave 0: lanes 0..31 gather this sample's 32 partial rows, butterfly,
    // lane 0 solves (a,b) in fp32 (det ~ 1e10, no cancellation; threshold 1.6e-2)
    if (threadIdx.x < 64) {
        const int l = threadIdx.x;
        float q0 = 0.f, q1 = 0.f, q2 = 0.f, q3 = 0.f, q4 = 0.f;
        if (l < 32) {
            const float* q = partials + (size_t)(s * 32 + l) * 5;
            q0 = q[0]; q1 = q[1]; q2 = q[2]; q3 = q[3]; q4 = q[4];
        }
#pragma unroll
        for (int off = 16; off; off >>= 1) {
            q0 += __shfl_xor(q0, off);
            q1 += __shfl_xor(q1, off);
            q2 += __shfl_xor(q2, off);
            q3 += __shfl_xor(q3, off);
            q4 += __shfl_xor(q4, off);
        }
        if (l == 0) {
            float det = q0 * q3 - q1 * q1;
            bool safe = fabsf(det) > EPS_DET;
            float a  = safe ? (q0 * q4 - q1 * q2) / det : 1.f;
            float bb = safe ? (q2 - a * q1) / fmaxf(q0, 1.f) : 0.f;
            smem[20] = a;
            smem[21] = bb;
        }
    }
    __syncthreads();
    const float av = smem[20];
    const float bv = smem[21];

    float r = 0.f;
    auto raccum = [&](float p, float t, bool mv) {
        bool ok = mv && finitef(p) && finitef(t);
        r += ok ? fabsf(av * p + bv - t) : 0.f;
    };

    if (byteLayout) {
        const unsigned* m4 = (const unsigned*)mask;
        for (int k = 0; k < FULL_IT; ++k) {
            const int i4 = base4 + k * TPB + threadIdx.x;
            float4 p = p4[i4]; float4 t = t4[i4]; unsigned mm = m4[i4];
            raccum(p.x, t.x, (mm & 0x000000ffu) != 0);
            raccum(p.y, t.y, (mm & 0x0000ff00u) != 0);
            raccum(p.z, t.z, (mm & 0x00ff0000u) != 0);
            raccum(p.w, t.w, (mm & 0xff000000u) != 0);
        }
        if (threadIdx.x < TAILN) {
            const int i4 = base4 + FULL_IT * TPB + threadIdx.x;
            float4 p = p4[i4]; float4 t = t4[i4]; unsigned mm = m4[i4];
            raccum(p.x, t.x, (mm & 0x000000ffu) != 0);
            raccum(p.y, t.y, (mm & 0x0000ff00u) != 0);
            raccum(p.z, t.z, (mm & 0x00ff0000u) != 0);
            raccum(p.w, t.w, (mm & 0xff000000u) != 0);
        }
    } else {
        const int4* m4 = (const int4*)mask;
        for (int k = 0; k < FULL_IT; ++k) {
            const int i4 = base4 + k * TPB + threadIdx.x;
            float4 p = p4[i4]; float4 t = t4[i4]; int4 mm = m4[i4];
            raccum(p.x, t.x, mm.x != 0);
            raccum(p.y, t.y, mm.y != 0);
            raccum(p.z, t.z, mm.z != 0);
            raccum(p.w, t.w, mm.w != 0);
        }
        if (threadIdx.x < TAILN) {
            const int i4 = base4 + FULL_IT * TPB + threadIdx.x;
            float4 p = p4[i4]; float4 t = t4[i4]; int4 mm = m4[i4];
            raccum(p.x, t.x, mm.x != 0);
            raccum(p.y, t.y, mm.y != 0);
            raccum(p.z, t.z, mm.z != 0);
            raccum(p.w, t.w, mm.w != 0);
        }
    }

    __syncthreads();   // smem[20..21] reads done before reuse below
    {
        float v = r;
#pragma unroll
        for (int off = 32; off; off >>= 1) v += __shfl_xor(v, off);
        if (lane == 0) smem[w] = v;
        __syncthreads();
        if (threadIdx.x == 0)
            rpart[blockIdx.x] = smem[0] + smem[1] + smem[2] + smem[3];
    }
    __threadfence();
    grid.sync();

    // ---------------- phase 3: final reduce (block 0) ----------------
    if (blockIdx.x == 0) {
        float* s_r = smem;            // [2048]
        float* s_n = smem + 2048;     // [2048]
#pragma unroll
        for (int k = 0; k < NBLK / TPB; ++k) {      // 8 coalesced rounds
            const int idx = k * TPB + threadIdx.x;
            s_r[idx] = rpart[idx];
            s_n[idx] = partials[(size_t)idx * 5];
        }
        __syncthreads();
        if (threadIdx.x < 64) {
            const int ss = threadIdx.x;             // one sample per lane
            float rr = 0.f, nn = 0.f;
            for (int b = 0; b < 32; ++b) {
                rr += s_r[ss * 32 + b];
                nn += s_n[ss * 32 + b];
            }
            float per = rr / fmaxf(nn, 1.f);
            float inc = (nn >= 2.f) ? 1.f : 0.f;
            float v = per * inc;
#pragma unroll
            for (int off = 32; off; off >>= 1) {
                v   += __shfl_xor(v, off);
                inc += __shfl_xor(inc, off);
            }
            if (ss == 0) out[0] = (inc > 0.f) ? v / fmaxf(inc, 1.f) : 0.f;
        }
    }
}

extern "C" void kernel_launch(void* const* d_in, const int* in_sizes, int n_in,
                              void* d_out, int out_size, void* d_ws, size_t ws_size,
                              hipStream_t stream) {
    const float* pred = (const float*)d_in[0];
    const float* target = (const float*)d_in[1];
    const unsigned char* mask = (const unsigned char*)d_in[2];
    float* out = (float*)d_out;

    // workspace layout
    int* flag = (int*)d_ws;                                // [0, 4)
    float* partials = (float*)((char*)d_ws + 64);          // 2048*5 fp32
    float* rpart = partials + (size_t)NBLK * 5;            // 2048 fp32

    hipMemsetAsync(d_ws, 0, 64, stream);   // zero detection flag

    void* args[] = {(void*)&pred, (void*)&target, (void*)&mask,
                    (void*)&flag, (void*)&partials, (void*)&rpart, (void*)&out};
    hipLaunchCooperativeKernel((const void*)fused, dim3(NBLK), dim3(TPB),
                               args, 0, stream);
}

// Round 6
// 79.940 us; speedup vs baseline: 11.1427x; 11.1427x over previous
//
#include <hip/hip_runtime.h>

// Problem constants (reference shape (64,1,480,640) fp32)
#define B_SAMPLES 64
#define F4PS      76800      // float4 per sample
#define BPS       30         // blocks per sample
#define F4PB      2560       // float4 per block
#define TPB       256        // threads per block
#define ITERS     10         // F4PB / TPB
#define WPB       4          // waves per block
#define EPS_DET   1e-6f

typedef __attribute__((address_space(3))) void       lds_void;
typedef const __attribute__((address_space(1))) void gbl_void;

__device__ __forceinline__ bool finitef(float x) {
    return (__float_as_uint(x) & 0x7f800000u) != 0x7f800000u;
}

// ---------------------------------------------------------------------------
// Local mask-layout detection: each block scans 4 KiB of ITS OWN mask chunk.
// int32 0/1 => bytes at 4k+{1,2,3} all zero; byte-bool => ~50% of ~3072
// scanned high-bytes nonzero (P[miss] ~ 2^-3072). No global flag needed.
// ---------------------------------------------------------------------------
__device__ __forceinline__ bool detect_byte_layout(const void* mask, int base4,
                                                   int* sflag) {
    const uint4* m16 =
        (const uint4*)((const unsigned char*)mask + (size_t)base4 * 4);
    uint4 m = m16[threadIdx.x];                     // 256 thr x 16 B = 4 KiB
    unsigned v = (m.x | m.y | m.z | m.w) & 0xffffff00u;
    if (threadIdx.x == 0) *sflag = 0;
    __syncthreads();
    if (__any(v != 0) && (threadIdx.x & 63) == 0) *sflag = 1;
    __syncthreads();
    return *sflag != 0;
}

// ---------------------------------------------------------------------------
// Async stage of one wave-tile (64 lanes): p 1KB, t 1KB, mask 256B -> LDS.
// LDS dest = wave-uniform base + lane*size (HW rule); global addr per-lane.
// ---------------------------------------------------------------------------
__device__ __forceinline__ void stage3(const float4* gp, const float4* gt,
                                       const unsigned* gm,
                                       unsigned char* lbuf) {
    __builtin_amdgcn_global_load_lds((gbl_void*)gp, (lds_void*)lbuf, 16, 0, 0);
    __builtin_amdgcn_global_load_lds((gbl_void*)gt, (lds_void*)(lbuf + 1024),
                                     16, 0, 0);
    __builtin_amdgcn_global_load_lds((gbl_void*)gm, (lds_void*)(lbuf + 2048),
                                     4, 0, 0);
}

// ---------------------------------------------------------------------------
// Kernel 1: per-block masked partial sums {n, sum_p, sum_t, sum_p2, sum_pt}
// Byte-mask path: 2-deep LDS pipeline via global_load_lds + counted vmcnt.
// Per wave: stage tile t+1 while consuming tile t; no barriers in loop.
// ---------------------------------------------------------------------------
__global__ void
sums_kernel(const float* __restrict__ pred, const float* __restrict__ target,
            const void* __restrict__ mask, float* __restrict__ partials) {
    const int s   = blockIdx.x / BPS;
    const int sub = blockIdx.x % BPS;
    const int base4 = s * F4PS + sub * F4PB;
    const int tid = threadIdx.x, lane = tid & 63, w = tid >> 6;

    __shared__ __align__(16) unsigned char stg[WPB][2][2304];
    __shared__ float red[WPB][5];
    __shared__ int sflag;

    const bool byteLayout = detect_byte_layout(mask, base4, &sflag);

    const float4* p4 = (const float4*)pred;
    const float4* t4 = (const float4*)target;

    float n = 0.f, sp = 0.f, st = 0.f, sp2 = 0.f, spt = 0.f;
    auto accum = [&](float p, float t, bool mv) {
        bool ok = mv && finitef(p) && finitef(t);
        float pv = ok ? p : 0.f;
        float tv = ok ? t : 0.f;
        n   += ok ? 1.f : 0.f;
        sp  += pv;
        st  += tv;
        sp2 += pv * pv;
        spt += pv * tv;
    };

    if (byteLayout) {
        const unsigned* m4 = (const unsigned*)mask;
        unsigned char* buf0 = &stg[w][0][0];     // wave-uniform
        unsigned char* buf1 = &stg[w][1][0];
        const int i0 = base4 + w * 64 + lane;
        stage3(p4 + i0, t4 + i0, m4 + i0, buf0);  // prologue: tile 0
#pragma unroll
        for (int t = 0; t < ITERS; ++t) {
            unsigned char* cur = (t & 1) ? buf1 : buf0;
            unsigned char* nxt = (t & 1) ? buf0 : buf1;
            if (t < ITERS - 1) {
                const int i4 = i0 + (t + 1) * TPB;
                stage3(p4 + i4, t4 + i4, m4 + i4, nxt);
                __builtin_amdgcn_sched_barrier(0);
                asm volatile("s_waitcnt vmcnt(3)" ::: "memory");
            } else {
                __builtin_amdgcn_sched_barrier(0);
                asm volatile("s_waitcnt vmcnt(0)" ::: "memory");
            }
            __builtin_amdgcn_sched_barrier(0);
            const float4  pv = *(const float4*)(cur + (size_t)lane * 16);
            const float4  tv = *(const float4*)(cur + 1024 + (size_t)lane * 16);
            const unsigned mm = *(const unsigned*)(cur + 2048 + (size_t)lane * 4);
            accum(pv.x, tv.x, (mm & 0x000000ffu) != 0);
            accum(pv.y, tv.y, (mm & 0x0000ff00u) != 0);
            accum(pv.z, tv.z, (mm & 0x00ff0000u) != 0);
            accum(pv.w, tv.w, (mm & 0xff000000u) != 0);
        }
    } else {
        const int4* m4 = (const int4*)mask;
        for (int t = 0; t < ITERS; ++t) {
            const int i4 = base4 + t * TPB + tid;
            float4 p = p4[i4]; float4 tt = t4[i4]; int4 mm = m4[i4];
            accum(p.x, tt.x, mm.x != 0);
            accum(p.y, tt.y, mm.y != 0);
            accum(p.z, tt.z, mm.z != 0);
            accum(p.w, tt.w, mm.w != 0);
        }
    }

    // block reduce 5 quantities
    {
        float vals[5] = {n, sp, st, sp2, spt};
#pragma unroll
        for (int q = 0; q < 5; ++q) {
            float v = vals[q];
#pragma unroll
            for (int off = 32; off; off >>= 1) v += __shfl_xor(v, off);
            if (lane == 0) red[w][q] = v;
        }
        __syncthreads();
        if (tid == 0) {
#pragma unroll
            for (int q = 0; q < 5; ++q)
                partials[(size_t)blockIdx.x * 5 + q] =
                    red[0][q] + red[1][q] + red[2][q] + red[3][q];
        }
    }
}

// ---------------------------------------------------------------------------
// Kernel 2: solve (a,b) from own sample's partials (wave 0), then residual
// pass with the same 2-deep LDS pipeline.
// ---------------------------------------------------------------------------
__global__ void
resid_kernel(const float* __restrict__ pred, const float* __restrict__ target,
             const void* __restrict__ mask, const float* __restrict__ partials,
             float* __restrict__ rpart) {
    const int s   = blockIdx.x / BPS;
    const int sub = blockIdx.x % BPS;
    const int base4 = s * F4PS + sub * F4PB;
    const int tid = threadIdx.x, lane = tid & 63, w = tid >> 6;

    __shared__ __align__(16) unsigned char stg[WPB][2][2304];
    __shared__ float red[WPB];
    __shared__ float s_ab[2];
    __shared__ int sflag;

    const bool byteLayout = detect_byte_layout(mask, base4, &sflag);

    const float4* p4 = (const float4*)pred;
    const float4* t4 = (const float4*)target;
    const unsigned* m4b = (const unsigned*)mask;

    unsigned char* buf0 = &stg[w][0][0];
    unsigned char* buf1 = &stg[w][1][0];
    const int i0 = base4 + w * 64 + lane;
    if (byteLayout)
        stage3(p4 + i0, t4 + i0, m4b + i0, buf0);  // prefetch tile 0 early

    // wave 0: gather this sample's 30 partial rows, butterfly, lane 0 solves
    if (tid < 64) {
        float q0 = 0.f, q1 = 0.f, q2 = 0.f, q3 = 0.f, q4 = 0.f;
        if (tid < BPS) {
            const float* q = partials + (size_t)(s * BPS + tid) * 5;
            q0 = q[0]; q1 = q[1]; q2 = q[2]; q3 = q[3]; q4 = q[4];
        }
#pragma unroll
        for (int off = 32; off; off >>= 1) {
            q0 += __shfl_xor(q0, off);
            q1 += __shfl_xor(q1, off);
            q2 += __shfl_xor(q2, off);
            q3 += __shfl_xor(q3, off);
            q4 += __shfl_xor(q4, off);
        }
        if (tid == 0) {
            float det = q0 * q3 - q1 * q1;
            bool safe = fabsf(det) > EPS_DET;
            float a  = safe ? (q0 * q4 - q1 * q2) / det : 1.f;
            float bb = safe ? (q2 - a * q1) / fmaxf(q0, 1.f) : 0.f;
            s_ab[0] = a;
            s_ab[1] = bb;
        }
    }
    __syncthreads();           // also drains the prefetch (vmcnt 0) - benign
    const float av = s_ab[0];
    const float bv = s_ab[1];

    float r = 0.f;
    auto raccum = [&](float p, float t, bool mv) {
        bool ok = mv && finitef(p) && finitef(t);
        r += ok ? fabsf(av * p + bv - t) : 0.f;
    };

    if (byteLayout) {
#pragma unroll
        for (int t = 0; t < ITERS; ++t) {
            unsigned char* cur = (t & 1) ? buf1 : buf0;
            unsigned char* nxt = (t & 1) ? buf0 : buf1;
            if (t < ITERS - 1) {
                const int i4 = i0 + (t + 1) * TPB;
                stage3(p4 + i4, t4 + i4, m4b + i4, nxt);
                __builtin_amdgcn_sched_barrier(0);
                asm volatile("s_waitcnt vmcnt(3)" ::: "memory");
            } else {
                __builtin_amdgcn_sched_barrier(0);
                asm volatile("s_waitcnt vmcnt(0)" ::: "memory");
            }
            __builtin_amdgcn_sched_barrier(0);
            const float4  pv = *(const float4*)(cur + (size_t)lane * 16);
            const float4  tv = *(const float4*)(cur + 1024 + (size_t)lane * 16);
            const unsigned mm = *(const unsigned*)(cur + 2048 + (size_t)lane * 4);
            raccum(pv.x, tv.x, (mm & 0x000000ffu) != 0);
            raccum(pv.y, tv.y, (mm & 0x0000ff00u) != 0);
            raccum(pv.z, tv.z, (mm & 0x00ff0000u) != 0);
            raccum(pv.w, tv.w, (mm & 0xff000000u) != 0);
        }
    } else {
        const int4* m4 = (const int4*)mask;
        for (int t = 0; t < ITERS; ++t) {
            const int i4 = base4 + t * TPB + tid;
            float4 p = p4[i4]; float4 tt = t4[i4]; int4 mm = m4[i4];
            raccum(p.x, tt.x, mm.x != 0);
            raccum(p.y, tt.y, mm.y != 0);
            raccum(p.z, tt.z, mm.z != 0);
            raccum(p.w, tt.w, mm.w != 0);
        }
    }

    {
        float v = r;
#pragma unroll
        for (int off = 32; off; off >>= 1) v += __shfl_xor(v, off);
        if (lane == 0) red[w] = v;
        __syncthreads();
        if (tid == 0)
            rpart[blockIdx.x] = red[0] + red[1] + red[2] + red[3];
    }
}

// ---------------------------------------------------------------------------
// Kernel 3: final loss. One wave, thread s = sample s.
// ---------------------------------------------------------------------------
__global__ void final_kernel(const float* __restrict__ partials,
                             const float* __restrict__ rpart,
                             float* __restrict__ out) {
    const int s = threadIdx.x;  // 64 threads = 1 wave
    double r = 0, n = 0;
    for (int b = 0; b < BPS; ++b) {
        r += (double)rpart[s * BPS + b];
        n += (double)partials[(size_t)(s * BPS + b) * 5 + 0];
    }
    double per = r / fmax(n, 1.0);
    double inc = (n >= 2.0) ? 1.0 : 0.0;
    double v = per * inc;
#pragma unroll
    for (int off = 32; off; off >>= 1) {
        v += __shfl_down(v, off);
        inc += __shfl_down(inc, off);
    }
    if (s == 0) out[0] = (float)(inc > 0.0 ? v / fmax(inc, 1.0) : 0.0);
}

extern "C" void kernel_launch(void* const* d_in, const int* in_sizes, int n_in,
                              void* d_out, int out_size, void* d_ws, size_t ws_size,
                              hipStream_t stream) {
    const float* pred = (const float*)d_in[0];
    const float* target = (const float*)d_in[1];
    const void* mask = d_in[2];
    float* out = (float*)d_out;

    // workspace layout (everything written before read; no zeroing needed)
    float* partials = (float*)d_ws;                          // 1920*5 fp32
    float* rpart = partials + (size_t)B_SAMPLES * BPS * 5;   // 1920 fp32

    sums_kernel<<<B_SAMPLES * BPS, TPB, 0, stream>>>(pred, target, mask,
                                                     partials);
    resid_kernel<<<B_SAMPLES * BPS, TPB, 0, stream>>>(pred, target, mask,
                                                      partials, rpart);
    final_kernel<<<1, 64, 0, stream>>>(partials, rpart, out);
}